// Round 1
// baseline (487.224 us; speedup 1.0000x reference)
//
#include <hip/hip_runtime.h>
#include <math.h>

#define LAYERS 20
// cs table: 20 layers * 12 qubits * {cos, sin} = 480 floats
#define CS_FLOATS 480

// ---------------------------------------------------------------------------
// Pre-kernel: accurate cos/sin of theta/2 for layers 1..20 (weights[1:21]).
// cs[(l*12+j)*2] = cos, cs[(l*12+j)*2+1] = sin
// ---------------------------------------------------------------------------
__global__ void cs_precompute(const float* __restrict__ qp, float* __restrict__ cs) {
    int i = threadIdx.x;
    if (i < 240) {
        float t = 0.5f * qp[12 + i];   // skip row 0 of (21,12) params
        cs[2 * i]     = cosf(t);
        cs[2 * i + 1] = sinf(t);
    }
}

// ---------------------------------------------------------------------------
// Main kernel: one wave == one batch row. State layout:
//   amplitude index i (0..4095):  reg r = i >> 6 (bits 11..6), lane = i & 63.
//   qubit j -> index bit (11-j):  qubits 0..5 = reg bits 5..0,
//                                 qubits 6..11 = lane bits 5..0.
// Entangling layer (11 CNOTs) == fixed GF(2)-linear source map:
//   src_reg  = r ^ (r>>1) ^ ((r>>2)&5)            (static rename, free)
//   src_lane = lane ^ (lane>>1) ^ ((lane>>2)&5)   (one ds_bpermute per reg)
//              ^ 48 when dest reg bit0 (qubit 5) is set   (cross term b5->x6,x7)
// ---------------------------------------------------------------------------
template <bool PRE>
__global__ __launch_bounds__(256, 4)
void qsim(const float* __restrict__ feats,
          const float* __restrict__ qp,
          const float* __restrict__ cs,
          float* __restrict__ out)
{
    const int lane = threadIdx.x & 63;
    const int row  = blockIdx.x * 4 + (threadIdx.x >> 6);

    // bpermute byte addresses for the entangler (computed once)
    const int sl0 = lane ^ (lane >> 1) ^ ((lane >> 2) & 5);
    const int addr0 = sl0 << 2;
    const int addr1 = (sl0 ^ 48) << 2;

    // ---- load + tanh + amplitude embedding ----
    float st[64];
    const float* fr = feats + (size_t)row * 2048;
    float nrm = 0.f;
#pragma unroll
    for (int r = 0; r < 32; ++r) {
        float v = tanhf(fr[(r << 6) + lane]) * 1.5707963267948966f;
        st[r] = v;
        nrm += v * v;
    }
#pragma unroll
    for (int m = 32; m >= 1; m >>= 1) nrm += __shfl_xor(nrm, m, 64);
    nrm += 512.0f;                       // 2048 pad elements of 0.5^2
    const float inv = rsqrtf(nrm);
#pragma unroll
    for (int r = 0; r < 32; ++r) st[r] *= inv;
    const float padv = 0.5f * inv;
#pragma unroll
    for (int r = 32; r < 64; ++r) st[r] = padv;

    // ---- 20 circuit layers ----
    for (int l = 0; l < LAYERS; ++l) {
        // entangling layer: single permutation pass
        {
            float ns[64];
#pragma unroll
            for (int r = 0; r < 64; ++r) {
                const int sr = r ^ (r >> 1) ^ ((r >> 2) & 5);
                ns[r] = __int_as_float(__builtin_amdgcn_ds_bpermute(
                            (r & 1) ? addr1 : addr0, __float_as_int(st[sr])));
            }
#pragma unroll
            for (int r = 0; r < 64; ++r) st[r] = ns[r];
        }

        const float* csl = cs + l * 24;

        // RY on reg-bit qubits j = 0..5  (rmask = 32 >> j)  -- pure VALU
#pragma unroll
        for (int j = 0; j < 6; ++j) {
            float c, s;
            if constexpr (PRE) {
                c = csl[2 * j]; s = csl[2 * j + 1];
            } else {
                float t = 0.5f * qp[12 + l * 12 + j];
                __sincosf(t, &s, &c);
            }
            const int m = 32 >> j;
#pragma unroll
            for (int r = 0; r < 64; ++r) {
                if (!(r & m)) {
                    const float a0 = st[r], a1 = st[r | m];
                    st[r]     = c * a0 - s * a1;
                    st[r | m] = s * a0 + c * a1;
                }
            }
        }

        // RY on lane-bit qubits j = 6..11  (lmask = 32 >> (j-6))
#pragma unroll
        for (int j = 0; j < 6; ++j) {
            float c, s;
            if constexpr (PRE) {
                c = csl[12 + 2 * j]; s = csl[12 + 2 * j + 1];
            } else {
                float t = 0.5f * qp[12 + l * 12 + 6 + j];
                __sincosf(t, &s, &c);
            }
            const int m = 32 >> j;
            const float ssel = (lane & m) ? s : -s;
#pragma unroll
            for (int r = 0; r < 64; ++r) {
                const float p = __shfl_xor(st[r], m, 64);
                st[r] = c * st[r] + ssel * p;   // bit0: c*a0 - s*a1 ; bit1: s*a0 + c*a1
            }
        }
    }

    // ---- PauliZ expectation values ----
    float T = 0.f;
#pragma unroll
    for (int r = 0; r < 64; ++r) { st[r] *= st[r]; T += st[r]; }

    float part[12];
#pragma unroll
    for (int q = 0; q < 6; ++q) {            // reg-bit qubits: sign from reg bit
        const int m = 32 >> q;
        float S = 0.f;
#pragma unroll
        for (int r = 0; r < 64; ++r) if (r & m) S += st[r];
        part[q] = T - 2.f * S;
    }
#pragma unroll
    for (int q = 6; q < 12; ++q) {           // lane-bit qubits: sign from lane bit
        const int m = 32 >> (q - 6);
        part[q] = (lane & m) ? -T : T;
    }
#pragma unroll
    for (int q = 0; q < 12; ++q) {
#pragma unroll
        for (int m = 32; m >= 1; m >>= 1) part[q] += __shfl_xor(part[q], m, 64);
    }
    if (lane == 0) {
#pragma unroll
        for (int q = 0; q < 12; ++q) out[row * 12 + q] = part[q];
    }
}

// ---------------------------------------------------------------------------
extern "C" void kernel_launch(void* const* d_in, const int* in_sizes, int n_in,
                              void* d_out, int out_size, void* d_ws, size_t ws_size,
                              hipStream_t stream) {
    (void)in_sizes; (void)n_in; (void)out_size;
    const float* feats = (const float*)d_in[0];   // (4096, 2048) fp32
    const float* qp    = (const float*)d_in[1];   // (252,) fp32
    float* out = (float*)d_out;                   // (4096, 12) fp32

    if (ws_size >= CS_FLOATS * sizeof(float)) {
        float* cs = (float*)d_ws;
        cs_precompute<<<1, 256, 0, stream>>>(qp, cs);
        qsim<true><<<1024, 256, 0, stream>>>(feats, qp, cs, out);
    } else {
        qsim<false><<<1024, 256, 0, stream>>>(feats, qp, nullptr, out);
    }
}